// Round 14
// baseline (6111.793 us; speedup 1.0000x reference)
//
#include <hip/hip_runtime.h>
#include <hip/hip_bf16.h>

// RNN: h_t = tanh(x_t @ Wx + h_{t-1} @ Wh + b), B=32, S=1024, D=H=1024, fp32.
// Phase 1: Xp = x@Wx + b in-place into d_out (~87% of fp32 vector peak).
// Phase 2: ONE persistent kernel. R14 = 2-CHAIN INTERLEAVE per WG.
//   R13 lesson (hang): sc0 loads are workgroup-scope -> served by stale L1;
//   no XCD-scope load exists -> MALL RT is irreducible. So HIDE it: 4 pairs
//   x 64 WGs; WG = chain A (4 batches) + chain B (4 batches) x 16 cols.
//   Wh regs SHARED (cols only). While A's publish/gate/stage latency drains,
//   B computes, and vice versa. Per-chain sync = R12's replay-PROVEN protocol:
//   scalar counter gate + CFENCEs + RETURNING-swap publish (MALL commit-ack)
//   + post-barrier counter add. New math: 32-wide fold (5 rounds, output at
//   brev5(lane&31), 4 partials/output) - deterministic, absmax-checkable.

#define BB 32
#define SS 1024
#define DD 1024
#define HH 1024
#define NPAIR 4   // chain pairs; pair p = chains 2p,2p+1 = batches 8p..8p+7
#define WGN 256   // 4 pairs x 64 col-groups of 16

#define CFENCE() asm volatile("" ::: "memory")

typedef unsigned long long ull;

#define ALD(p) __hip_atomic_load((p), __ATOMIC_RELAXED, __HIP_MEMORY_SCOPE_AGENT)

// ---------------- Phase 1: C = A @ W + bias ----------------
__global__ __launch_bounds__(256) void xw_gemm(const float* __restrict__ A,
                                               const float* __restrict__ W,
                                               const float* __restrict__ bias,
                                               float* __restrict__ C) {
    __shared__ float As[8][132];
    __shared__ float Bs[8][132];
    const int tid = threadIdx.x;
    const int n0 = blockIdx.x * 128;
    const int m0 = blockIdx.y * 128;
    const int tx = tid & 15;
    const int ty = tid >> 4;
    const int ar = tid >> 1;
    const int ak = (tid & 1) * 4;
    const int bk = tid >> 5;
    const int bn = (tid & 31) * 4;

    float acc[8][8];
#pragma unroll
    for (int i = 0; i < 8; ++i)
#pragma unroll
        for (int j = 0; j < 8; ++j) acc[i][j] = 0.f;

    for (int k0 = 0; k0 < DD; k0 += 8) {
        float4 av = *(const float4*)(A + (size_t)(m0 + ar) * DD + k0 + ak);
        float4 bv = *(const float4*)(W + (size_t)(k0 + bk) * HH + n0 + bn);
        __syncthreads();
        As[ak + 0][ar] = av.x;
        As[ak + 1][ar] = av.y;
        As[ak + 2][ar] = av.z;
        As[ak + 3][ar] = av.w;
        *(float4*)&Bs[bk][bn] = bv;
        __syncthreads();
#pragma unroll
        for (int k = 0; k < 8; ++k) {
            float4 a0 = *(const float4*)&As[k][ty * 4];
            float4 a1 = *(const float4*)&As[k][64 + ty * 4];
            float4 b0 = *(const float4*)&Bs[k][tx * 4];
            float4 b1 = *(const float4*)&Bs[k][64 + tx * 4];
            float ar_[8] = {a0.x, a0.y, a0.z, a0.w, a1.x, a1.y, a1.z, a1.w};
            float br_[8] = {b0.x, b0.y, b0.z, b0.w, b1.x, b1.y, b1.z, b1.w};
#pragma unroll
            for (int i = 0; i < 8; ++i)
#pragma unroll
                for (int j = 0; j < 8; ++j)
                    acc[i][j] = fmaf(ar_[i], br_[j], acc[i][j]);
        }
    }

    float4 bv0 = *(const float4*)(bias + n0 + tx * 4);
    float4 bv1 = *(const float4*)(bias + n0 + 64 + tx * 4);
#pragma unroll
    for (int i = 0; i < 8; ++i) {
        int m = m0 + ((i < 4) ? (ty * 4 + i) : (64 + ty * 4 + (i - 4)));
        float4 r0 = {acc[i][0] + bv0.x, acc[i][1] + bv0.y,
                     acc[i][2] + bv0.z, acc[i][3] + bv0.w};
        float4 r1 = {acc[i][4] + bv1.x, acc[i][5] + bv1.y,
                     acc[i][6] + bv1.z, acc[i][7] + bv1.w};
        *(float4*)(C + (size_t)m * HH + n0 + tx * 4) = r0;
        *(float4*)(C + (size_t)m * HH + n0 + 64 + tx * 4) = r1;
    }
}

// ---------------- WhT[n][k] = Wh[k][n] ----------------
__global__ __launch_bounds__(256) void transpose_wh(const float* __restrict__ in,
                                                    float* __restrict__ outT) {
    __shared__ float tile[32][33];
    const int tx = threadIdx.x & 31;
    const int ty = threadIdx.x >> 5;
    const int x0 = blockIdx.x * 32;
    const int y0 = blockIdx.y * 32;
    for (int r = ty; r < 32; r += 8)
        tile[r][tx] = in[(size_t)(y0 + r) * HH + x0 + tx];
    __syncthreads();
    for (int r = ty; r < 32; r += 8)
        outT[(size_t)(x0 + r) * HH + y0 + tx] = tile[tx][r];
}

// ---------------- Persistent RNN, 2 chains per WG ----------------
// WG(p,ng): chain A = batches 8p..8p+3, chain B = 8p+4..8p+7, cols n0..n0+15.
// Thread tile per chain: 4b x 8n x 8k (ns=tid>>7 col-octet, kq=tid&127).
#define FMA4(HSB, ACC, HALF)                                                   \
    {                                                                          \
        const int kb = (HALF) * 512 + kq * 4;                                  \
        float4 h_[4];                                                          \
        _Pragma("unroll") for (int b = 0; b < 4; ++b)                          \
            h_[b] = *(const float4*)&HSB[b][kb];                               \
        _Pragma("unroll") for (int b = 0; b < 4; ++b)                          \
            _Pragma("unroll") for (int c = 0; c < 8; ++c)                      \
                ACC[b * 8 + c] += h_[b].x * wreg[HALF][c].x +                  \
                                  h_[b].y * wreg[HALF][c].y +                  \
                                  h_[b].z * wreg[HALF][c].z +                  \
                                  h_[b].w * wreg[HALF][c].w;                   \
    }

// fold 32 values over 64 lanes (5 rounds). Result: lane l holds the partial
// sum (over its 32-lane bit5 group) of output o = brev5(l & 31).
#define FOLD32(ACC)                                                            \
    {                                                                          \
        int s_ = 32;                                                           \
        _Pragma("unroll") for (int m = 1; m <= 16; m <<= 1) {                  \
            const int hh_ = s_ >> 1;                                           \
            const bool hi = (lane & m) != 0;                                   \
            _Pragma("unroll") for (int i = 0; i < hh_; ++i) {                  \
                float lo = ACC[i], hg = ACC[i + hh_];                          \
                ACC[i]       = hi ? hg : lo;                                   \
                ACC[i + hh_] = hi ? lo : hg;                                   \
            }                                                                  \
            _Pragma("unroll") for (int i = 0; i < hh_; ++i)                    \
                ACC[i] += __shfl_xor(ACC[i + hh_], m, 64);                     \
            s_ = hh_;                                                          \
        }                                                                      \
    }

__global__ __launch_bounds__(256, 1) void rnn_persist(
    const float* __restrict__ Wh, const float* __restrict__ WhT,
    const float* __restrict__ h0, float* __restrict__ out,
    unsigned int* __restrict__ flags, float* __restrict__ hbuf) {
    __shared__ float hsA[4][1024];   // 16KB h of chain A
    __shared__ float hsB[4][1024];   // 16KB h of chain B
    __shared__ float red[4][64];
    __shared__ float houtA[4][16];
    __shared__ float houtB[4][16];

    const int tid  = threadIdx.x;
    const int p    = blockIdx.x & 3;
    const int ng   = blockIdx.x >> 2;   // 0..63
    const int n0   = ng * 16;
    const int b0A  = p * 8;
    const int b0B  = p * 8 + 4;
    const int lane = tid & 63;
    const int wv   = tid >> 6;
    const int ns   = tid >> 7;
    const int kq   = tid & 127;
    unsigned int* cntA = flags + (2 * p) * 64;
    unsigned int* cntB = flags + (2 * p + 1) * 64;

    // --- one-time: Wh fragment (cols n0+ns*8..+7, shared by both chains) ---
    float4 wreg[2][8];
    if (WhT) {
        const float* base = WhT + (size_t)(n0 + ns * 8) * HH + kq * 4;
#pragma unroll
        for (int c = 0; c < 8; ++c) {
            wreg[0][c] = *(const float4*)(base + (size_t)c * HH);
            wreg[1][c] = *(const float4*)(base + (size_t)c * HH + 512);
        }
    } else {
#pragma unroll
        for (int c = 0; c < 8; ++c) {
            float v[8];
            for (int j = 0; j < 4; ++j)
                v[j] = Wh[(size_t)(kq * 4 + j) * HH + n0 + ns * 8 + c];
            for (int j = 0; j < 4; ++j)
                v[4 + j] = Wh[(size_t)(512 + kq * 4 + j) * HH + n0 + ns * 8 + c];
            wreg[0][c] = {v[0], v[1], v[2], v[3]};
            wreg[1][c] = {v[4], v[5], v[6], v[7]};
        }
    }

    // combine/epilogue mapping: tid<64 -> chain A output, tid in [64,128) -> B
    size_t xp_base = 0;
    int eb = 0, ec = 0, l5 = 0, nso = 0;
    if (tid < 128) {
        int ct = tid & 63;
        nso = ct >> 5;
        int o = ct & 31;
        eb = o >> 3;                       // 0..3
        ec = nso * 8 + (o & 7);            // 0..15
        l5 = (int)(__brev((unsigned)o) >> 27);
        int myb0 = (tid < 64) ? b0A : b0B;
        xp_base = ((size_t)(myb0 + eb) * SS) * HH + (n0 + ec);
    }

    for (int t = 0; t < SS; ++t) {
        // ---- prefetch own Xp (plain load, independent of sync) ----
        float xp = 0.f;
        if (tid < 128) xp = out[xp_base + (size_t)t * HH];

        ull hrB[8];
        const ull* hsrc = (const ull*)(hbuf + (size_t)((t - 1) & 1) * BB * HH);

        if (t == 0) {
            int c4 = tid * 4;
            float4 v = *(const float4*)(h0 + c4);
#pragma unroll
            for (int j = 0; j < 4; ++j) {
                *(float4*)&hsA[j][c4] = v;
                *(float4*)&hsB[j][c4] = v;
            }
            __syncthreads();
        } else {
            // ---- gate A, stage A; gate B under the A-load shadow ----
            if (tid == 0) {
                const unsigned target = (unsigned)t * 64u;
                while (ALD(cntA) < target) {
                }
            }
            CFENCE();
            __syncthreads();
            CFENCE();
            ull hrA[8];
#pragma unroll
            for (int j = 0; j < 4; ++j)
                hrA[j] = ALD(hsrc + (size_t)(b0A + j) * 512 + tid);
#pragma unroll
            for (int j = 0; j < 4; ++j)
                hrA[4 + j] = ALD(hsrc + (size_t)(b0A + j) * 512 + 256 + tid);
            if (tid == 0) {
                const unsigned target = (unsigned)t * 64u;
                while (ALD(cntB) < target) {
                }
            }
#pragma unroll
            for (int j = 0; j < 4; ++j) {
                *(ull*)&hsA[j][tid * 2] = hrA[j];
                *(ull*)&hsA[j][512 + tid * 2] = hrA[4 + j];
            }
            CFENCE();
            __syncthreads();   // releases B gate + hsA ready
            CFENCE();
            // issue B staging loads now; they fly under A's compute
#pragma unroll
            for (int j = 0; j < 4; ++j)
                hrB[j] = ALD(hsrc + (size_t)(b0B + j) * 512 + tid);
#pragma unroll
            for (int j = 0; j < 4; ++j)
                hrB[4 + j] = ALD(hsrc + (size_t)(b0B + j) * 512 + 256 + tid);
        }

        // ================= phase A =================
        float aA[32];
#pragma unroll
        for (int i = 0; i < 32; ++i) aA[i] = 0.f;
        FMA4(hsA, aA, 0)
        FMA4(hsA, aA, 1)
        FOLD32(aA)
        red[wv][lane] = aA[0];
        __syncthreads();

        if (tid < 64) {
            float v = red[2 * nso][l5] + red[2 * nso][l5 + 32] +
                      red[2 * nso + 1][l5] + red[2 * nso + 1][l5 + 32];
            float hv = tanhf(v + xp);
            out[xp_base + (size_t)t * HH] = hv;
            houtA[eb][ec] = hv;
        }
        __syncthreads();

        if (tid < 32) {   // publish A: returning swaps (MALL commit-ack)
            const int r  = tid >> 3;
            const int c2 = tid & 7;
            ull u = *(const ull*)&houtA[r][c2 * 2];
            ull* ptr = (ull*)(hbuf + (size_t)(t & 1) * BB * HH) +
                       (size_t)(b0A + r) * 512 + ng * 8 + c2;
            ull old = __hip_atomic_exchange(ptr, u, __ATOMIC_RELAXED,
                                            __HIP_MEMORY_SCOPE_AGENT);
            asm volatile("" ::"v"(old));
        }
        if (t > 0) {      // land B staging into LDS (loads issued pre-A)
#pragma unroll
            for (int j = 0; j < 4; ++j) {
                *(ull*)&hsB[j][tid * 2] = hrB[j];
                *(ull*)&hsB[j][512 + tid * 2] = hrB[4 + j];
            }
        }
        CFENCE();
        __syncthreads();   // drains publish acks + hsB writes
        CFENCE();
        if (tid == 0)
            __hip_atomic_fetch_add(cntA, 1u, __ATOMIC_RELAXED,
                                   __HIP_MEMORY_SCOPE_AGENT);

        // ================= phase B =================
        float aB[32];
#pragma unroll
        for (int i = 0; i < 32; ++i) aB[i] = 0.f;
        FMA4(hsB, aB, 0)
        FMA4(hsB, aB, 1)
        FOLD32(aB)
        red[wv][lane] = aB[0];
        __syncthreads();

        if (tid >= 64 && tid < 128) {
            float v = red[2 * nso][l5] + red[2 * nso][l5 + 32] +
                      red[2 * nso + 1][l5] + red[2 * nso + 1][l5 + 32];
            float hv = tanhf(v + xp);
            out[xp_base + (size_t)t * HH] = hv;
            houtB[eb][ec] = hv;
        }
        __syncthreads();

        if (tid < 32) {   // publish B
            const int r  = tid >> 3;
            const int c2 = tid & 7;
            ull u = *(const ull*)&houtB[r][c2 * 2];
            ull* ptr = (ull*)(hbuf + (size_t)(t & 1) * BB * HH) +
                       (size_t)(b0B + r) * 512 + ng * 8 + c2;
            ull old = __hip_atomic_exchange(ptr, u, __ATOMIC_RELAXED,
                                            __HIP_MEMORY_SCOPE_AGENT);
            asm volatile("" ::"v"(old));
        }
        CFENCE();
        __syncthreads();
        CFENCE();
        if (tid == 0)
            __hip_atomic_fetch_add(cntB, 1u, __ATOMIC_RELAXED,
                                   __HIP_MEMORY_SCOPE_AGENT);
    }
}

// ---------------- fallback path (tiny ws): multi-launch steps ----------------
__global__ __launch_bounds__(256) void h0wh(const float* __restrict__ Wh,
                                            const float* __restrict__ h0,
                                            float* __restrict__ c) {
    const int g = blockIdx.x;
    const int n = threadIdx.x * 4;
    float4 a = {0.f, 0.f, 0.f, 0.f};
    for (int kk = 0; kk < 16; ++kk) {
        int k = g * 16 + kk;
        float hv = h0[k];
        float4 w = *(const float4*)(Wh + (size_t)k * HH + n);
        a.x += hv * w.x; a.y += hv * w.y; a.z += hv * w.z; a.w += hv * w.w;
    }
    atomicAdd(&c[n + 0], a.x);
    atomicAdd(&c[n + 1], a.y);
    atomicAdd(&c[n + 2], a.z);
    atomicAdd(&c[n + 3], a.w);
}

__global__ __launch_bounds__(256) void t0_kernel(float* __restrict__ out,
                                                 const float* __restrict__ c) {
    const int idx = blockIdx.x * 256 + threadIdx.x;
    const int b = idx >> 10;
    const int n = idx & 1023;
    const size_t p = (size_t)b * SS * HH + n;
    out[p] = tanhf(out[p] + c[n]);
}

__global__ __launch_bounds__(256) void rnn_step(const float* __restrict__ Wh,
                                                float* __restrict__ out, int t) {
    __shared__ float hsl[8][1028];
    __shared__ float ps[256];
    const int tid = threadIdx.x;
    const int n0 = blockIdx.x * 16;
    const int b0 = blockIdx.y * 8;
    for (int i = tid; i < 8 * 256; i += 256) {
        int r = i >> 8;
        int c = (i & 255) << 2;
        *(float4*)&hsl[r][c] =
            *(const float4*)(out + ((size_t)(b0 + r) * SS + (t - 1)) * HH + c);
    }
    __syncthreads();
    const int nl = tid & 15;
    const int bl = (tid >> 4) & 7;
    const int half_ = tid >> 7;
    const int n = n0 + nl;
    float acc = 0.f;
    const float* hrow = &hsl[bl][half_ * 512];
    const float* wcol = Wh + (size_t)(half_ * 512) * HH + n;
#pragma unroll 4
    for (int k = 0; k < 512; k += 4) {
        float4 h4 = *(const float4*)(hrow + k);
        acc += h4.x * wcol[(size_t)(k + 0) * HH];
        acc += h4.y * wcol[(size_t)(k + 1) * HH];
        acc += h4.z * wcol[(size_t)(k + 2) * HH];
        acc += h4.w * wcol[(size_t)(k + 3) * HH];
    }
    ps[tid] = acc;
    __syncthreads();
    if (tid < 128) {
        const size_t obase = ((size_t)(b0 + bl) * SS + t) * HH + n;
        out[obase] = tanhf(out[obase] + ps[tid] + ps[tid + 128]);
    }
}

extern "C" void kernel_launch(void* const* d_in, const int* in_sizes, int n_in,
                              void* d_out, int out_size, void* d_ws, size_t ws_size,
                              hipStream_t stream) {
    const float* x    = (const float*)d_in[0];
    const float* Wx   = (const float*)d_in[1];
    const float* Wh   = (const float*)d_in[2];
    const float* bias = (const float*)d_in[3];
    const float* h0   = (const float*)d_in[4];
    float* out = (float*)d_out;
    float* ws  = (float*)d_ws;

    // Phase 1: Xp = x@Wx + b -> d_out
    xw_gemm<<<dim3(8, 256), 256, 0, stream>>>(x, Wx, bias, out);

    // ws layout: [0..511] counters (uint) | [512..] hbuf 2*32*1024 f | WhT 1024^2 f
    const size_t need_persist = (size_t)(512 + 2 * BB * HH) * sizeof(float);
    const size_t need_wht     = need_persist + (size_t)HH * HH * sizeof(float);

    if (ws_size >= need_persist) {
        unsigned int* flags = (unsigned int*)ws;
        float* hbuf = ws + 512;
        hipMemsetAsync(flags, 0, 2048, stream);

        const float* WhT = nullptr;
        if (ws_size >= need_wht) {
            float* whtp = ws + 512 + 2 * BB * HH;
            transpose_wh<<<dim3(32, 32), 256, 0, stream>>>(Wh, whtp);
            WhT = whtp;
        }

        void* kargs[] = {(void*)&Wh, (void*)&WhT, (void*)&h0, (void*)&out,
                         (void*)&flags, (void*)&hbuf};
        hipError_t rc = hipLaunchCooperativeKernel((const void*)rnn_persist,
                                                   dim3(WGN), dim3(256), kargs, 0,
                                                   stream);
        if (rc != hipSuccess) {
            rnn_persist<<<dim3(WGN), dim3(256), 0, stream>>>(Wh, WhT, h0, out,
                                                             flags, hbuf);
        }
    } else {
        // emergency fallback: multi-launch (correct, slow)
        float* cvec = ws;  // 1024 floats
        hipMemsetAsync(cvec, 0, HH * sizeof(float), stream);
        h0wh<<<64, 256, 0, stream>>>(Wh, h0, cvec);
        t0_kernel<<<BB * HH / 256, 256, 0, stream>>>(out, cvec);
        for (int t = 1; t < SS; ++t)
            rnn_step<<<dim3(64, 4), 256, 0, stream>>>(Wh, out, t);
    }
}

// Round 15
// 5260.765 us; speedup vs baseline: 1.1618x; 1.1618x over previous
//
#include <hip/hip_runtime.h>
#include <hip/hip_bf16.h>

// RNN: h_t = tanh(x_t @ Wx + h_{t-1} @ Wh + b), B=32, S=1024, D=H=1024, fp32.
// Phase 1: Xp = x@Wx + b in-place into d_out (~87% of fp32 vector peak).
// Phase 2: ONE persistent kernel, 8 chains x 32 WGs x (4b x 32n) = R12 geometry.
// R15 = R12 with the gate's RMW tail removed: per-WG FLAG stores (parallel
//   MALL service) + one 64-lane poll, instead of 32 serialized fetch_adds.
//   Soundness: R12's RETURNING-xchg publish proves data commit BEFORE the
//   flag store issues (xchg return -> barrier -> flag store); a store's
//   visibility time >= its issue time > data-commit time, so a consumer
//   observing flag>=t reads committed h. (R8's flag failure is attributed
//   to its PLAIN-store publish, falsifiable by this round.)
//   R14 lesson: 2-chain interleave serializes phases in-stream -> regression.

#define BB 32
#define SS 1024
#define DD 1024
#define HH 1024
#define NG 32   // n-groups of 32 cols
#define BG 8    // b-groups (chains) of 4 batches
#define WGN (NG * BG)

#define CFENCE() asm volatile("" ::: "memory")

typedef unsigned long long ull;

// ---------------- Phase 1: C = A @ W + bias ----------------
__global__ __launch_bounds__(256) void xw_gemm(const float* __restrict__ A,
                                               const float* __restrict__ W,
                                               const float* __restrict__ bias,
                                               float* __restrict__ C) {
    __shared__ float As[8][132];
    __shared__ float Bs[8][132];
    const int tid = threadIdx.x;
    const int n0 = blockIdx.x * 128;
    const int m0 = blockIdx.y * 128;
    const int tx = tid & 15;
    const int ty = tid >> 4;
    const int ar = tid >> 1;
    const int ak = (tid & 1) * 4;
    const int bk = tid >> 5;
    const int bn = (tid & 31) * 4;

    float acc[8][8];
#pragma unroll
    for (int i = 0; i < 8; ++i)
#pragma unroll
        for (int j = 0; j < 8; ++j) acc[i][j] = 0.f;

    for (int k0 = 0; k0 < DD; k0 += 8) {
        float4 av = *(const float4*)(A + (size_t)(m0 + ar) * DD + k0 + ak);
        float4 bv = *(const float4*)(W + (size_t)(k0 + bk) * HH + n0 + bn);
        __syncthreads();
        As[ak + 0][ar] = av.x;
        As[ak + 1][ar] = av.y;
        As[ak + 2][ar] = av.z;
        As[ak + 3][ar] = av.w;
        *(float4*)&Bs[bk][bn] = bv;
        __syncthreads();
#pragma unroll
        for (int k = 0; k < 8; ++k) {
            float4 a0 = *(const float4*)&As[k][ty * 4];
            float4 a1 = *(const float4*)&As[k][64 + ty * 4];
            float4 b0 = *(const float4*)&Bs[k][tx * 4];
            float4 b1 = *(const float4*)&Bs[k][64 + tx * 4];
            float ar_[8] = {a0.x, a0.y, a0.z, a0.w, a1.x, a1.y, a1.z, a1.w};
            float br_[8] = {b0.x, b0.y, b0.z, b0.w, b1.x, b1.y, b1.z, b1.w};
#pragma unroll
            for (int i = 0; i < 8; ++i)
#pragma unroll
                for (int j = 0; j < 8; ++j)
                    acc[i][j] = fmaf(ar_[i], br_[j], acc[i][j]);
        }
    }

    float4 bv0 = *(const float4*)(bias + n0 + tx * 4);
    float4 bv1 = *(const float4*)(bias + n0 + 64 + tx * 4);
#pragma unroll
    for (int i = 0; i < 8; ++i) {
        int m = m0 + ((i < 4) ? (ty * 4 + i) : (64 + ty * 4 + (i - 4)));
        float4 r0 = {acc[i][0] + bv0.x, acc[i][1] + bv0.y,
                     acc[i][2] + bv0.z, acc[i][3] + bv0.w};
        float4 r1 = {acc[i][4] + bv1.x, acc[i][5] + bv1.y,
                     acc[i][6] + bv1.z, acc[i][7] + bv1.w};
        *(float4*)(C + (size_t)m * HH + n0 + tx * 4) = r0;
        *(float4*)(C + (size_t)m * HH + n0 + 64 + tx * 4) = r1;
    }
}

// ---------------- WhT[n][k] = Wh[k][n] ----------------
__global__ __launch_bounds__(256) void transpose_wh(const float* __restrict__ in,
                                                    float* __restrict__ outT) {
    __shared__ float tile[32][33];
    const int tx = threadIdx.x & 31;
    const int ty = threadIdx.x >> 5;
    const int x0 = blockIdx.x * 32;
    const int y0 = blockIdx.y * 32;
    for (int r = ty; r < 32; r += 8)
        tile[r][tx] = in[(size_t)(y0 + r) * HH + x0 + tx];
    __syncthreads();
    for (int r = ty; r < 32; r += 8)
        outT[(size_t)(x0 + r) * HH + y0 + tx] = tile[tx][r];
}

// ---------------- Persistent RNN over all S steps ----------------
// WG(bg,ng): batches b0..b0+3, cols n0..n0+31. Thread tile 4b x 16n x 8k:
//   ns = tid>>7 (col half of 16), kq = tid&127 -> k in {4kq..+3} u {512+4kq..+3}.
#define FMA_HALF(HALF)                                                         \
    {                                                                          \
        const int kb = (HALF) * 512 + kq * 4;                                  \
        float4 h[4];                                                           \
        _Pragma("unroll") for (int b = 0; b < 4; ++b)                          \
            h[b] = *(const float4*)&hs[b][kb];                                 \
        _Pragma("unroll") for (int b = 0; b < 4; ++b)                          \
            _Pragma("unroll") for (int c = 0; c < 16; ++c)                     \
                a[b * 16 + c] += h[b].x * wreg[HALF][c].x +                    \
                                 h[b].y * wreg[HALF][c].y +                    \
                                 h[b].z * wreg[HALF][c].z +                    \
                                 h[b].w * wreg[HALF][c].w;                     \
    }

__global__ __launch_bounds__(256, 1) void rnn_persist(
    const float* __restrict__ Wh, const float* __restrict__ WhT,
    const float* __restrict__ h0, float* __restrict__ out,
    unsigned int* __restrict__ flags, float* __restrict__ hbuf) {
    __shared__ float hs[4][1024];    // 16KB [b][k]
    __shared__ float red[4][64];
    __shared__ float hout[4][32];    // linearized h tile for coalesced publish

    const int tid  = threadIdx.x;
    const int ng   = blockIdx.x & 31;
    const int bg   = blockIdx.x >> 5;
    const int n0   = ng * 32;
    const int b0   = bg * 4;
    const int lane = tid & 63;
    const int wv   = tid >> 6;
    const int ns   = tid >> 7;
    const int kq   = tid & 127;
    unsigned int* myflags = flags + bg * 64;  // 32 flag words per chain, 256B apart

    // --- one-time: this thread's Wh fragment into registers ---
    // cols n0+ns*16 .. +15 at k in {4kq..4kq+3} u {512+4kq..+3}
    float4 wreg[2][16];
    if (WhT) {
        const float* base = WhT + (size_t)(n0 + ns * 16) * HH + kq * 4;
#pragma unroll
        for (int c = 0; c < 16; ++c) {
            wreg[0][c] = *(const float4*)(base + (size_t)c * HH);
            wreg[1][c] = *(const float4*)(base + (size_t)c * HH + 512);
        }
    } else {
#pragma unroll
        for (int c = 0; c < 16; ++c) {
            float v[8];
            for (int j = 0; j < 4; ++j)
                v[j] = Wh[(size_t)(kq * 4 + j) * HH + n0 + ns * 16 + c];
            for (int j = 0; j < 4; ++j)
                v[4 + j] = Wh[(size_t)(512 + kq * 4 + j) * HH + n0 + ns * 16 + c];
            wreg[0][c] = {v[0], v[1], v[2], v[3]};
            wreg[1][c] = {v[4], v[5], v[6], v[7]};
        }
    }

    // epilogue mapping: thread (tid<128) owns output (eb, ec)
    size_t xp_base = 0;
    int eb = 0, ec = 0;
    if (tid < 128) {
        int l   = tid & 63;
        int idx = (int)(__brev((unsigned)l) >> 26);  // 6-bit bit-reverse
        eb = idx >> 4;                                // 0..3
        ec = (tid >> 6) * 16 + (idx & 15);            // 0..31
        xp_base = ((size_t)(b0 + eb) * SS) * HH + (n0 + ec);
    }

    for (int t = 0; t < SS; ++t) {
        // ---- prefetch own Xp (plain load, independent of sync) ----
        float xp = 0.f;
        if (tid < 128) xp = out[xp_base + (size_t)t * HH];

        float a[64];
#pragma unroll
        for (int i = 0; i < 64; ++i) a[i] = 0.f;

        if (t == 0) {
#pragma unroll
            for (int j = 0; j < 4; ++j) {
                int f4 = tid + 256 * j;
                int r = f4 >> 8, c4 = (f4 & 255) * 4;
                *(float4*)&hs[r][c4] = *(const float4*)(h0 + c4);
            }
            __syncthreads();
            FMA_HALF(0)
            FMA_HALF(1)
        } else {
            // ---- gate: one 64-lane poll of the chain's 32 flags (no RMW
            //      tail; producer flag stores service in parallel) ----
            if (wv == 0) {
                const unsigned target = (unsigned)t;
                const int fidx = lane & 31;
                for (;;) {
                    unsigned v = __hip_atomic_load(&myflags[fidx], __ATOMIC_RELAXED,
                                                   __HIP_MEMORY_SCOPE_AGENT);
                    if (__all((int)(v >= target))) break;
                }
            }
            CFENCE();
            __syncthreads();
            CFENCE();   // block hoisting agent-scope loads above the gate

            // ---- async-stage split: issue ALL 8 sc1 loads, then
            //      write/compute half0 while half1 is still in flight ----
            const ull* hsrc = (const ull*)(hbuf + (size_t)((t - 1) & 1) * BB * HH);
            ull hr[8];
#pragma unroll
            for (int j = 0; j < 4; ++j)
                hr[j] = __hip_atomic_load(hsrc + (size_t)(b0 + j) * 512 + tid,
                                          __ATOMIC_RELAXED, __HIP_MEMORY_SCOPE_AGENT);
#pragma unroll
            for (int j = 0; j < 4; ++j)
                hr[4 + j] = __hip_atomic_load(hsrc + (size_t)(b0 + j) * 512 + 256 + tid,
                                              __ATOMIC_RELAXED, __HIP_MEMORY_SCOPE_AGENT);
#pragma unroll
            for (int j = 0; j < 4; ++j)
                *(ull*)&hs[j][tid * 2] = hr[j];
            __syncthreads();
            FMA_HALF(0)
#pragma unroll
            for (int j = 0; j < 4; ++j)
                *(ull*)&hs[j][512 + tid * 2] = hr[4 + j];
            __syncthreads();
            FMA_HALF(1)
        }

        // ---- folding in-wave reduce over kq ----
        int s = 64;
#pragma unroll
        for (int m = 1; m <= 32; m <<= 1) {
            const int hs_ = s >> 1;
            const bool hi = (lane & m) != 0;
#pragma unroll
            for (int i = 0; i < hs_; ++i) {
                float lo = a[i], hg = a[i + hs_];
                a[i]       = hi ? hg : lo;
                a[i + hs_] = hi ? lo : hg;
            }
#pragma unroll
            for (int i = 0; i < hs_; ++i) a[i] += __shfl_xor(a[i + hs_], m, 64);
            s = hs_;
        }

        red[wv][lane] = a[0];
        __syncthreads();

        // ---- epilogue: finalize, write out (plain), linearize into hout ----
        if (tid < 128) {
            const int l = tid & 63;
            const int nss = tid >> 6;
            float v = red[nss * 2][l] + red[nss * 2 + 1][l];
            float hv = tanhf(v + xp);
            out[xp_base + (size_t)t * HH] = hv;  // plain (write-only in-kernel)
            hout[eb][ec] = hv;
        }
        __syncthreads();

        // ---- publish via RETURNING atomic exchange: the old value's return
        //      proves MALL commit, so the barrier's vmcnt drain orders the
        //      flag store AFTER global visibility of h ----
        if (tid < 64) {
            const int r  = tid >> 4;   // 0..3
            const int c2 = tid & 15;   // 0..15 (x2 floats = 32 cols)
            ull u = *(const ull*)&hout[r][c2 * 2];
            ull old = __hip_atomic_exchange(
                (ull*)(hbuf + (size_t)(t & 1) * BB * HH) +
                    (size_t)(b0 + r) * 512 + (n0 >> 1) + c2,
                u, __ATOMIC_RELAXED, __HIP_MEMORY_SCOPE_AGENT);
            asm volatile("" ::"v"(old));  // keep return alive -> returning form
        }

        // ---- barrier waits all xchg returns (= MALL commits), then the
        //      per-WG flag store (parallel service, no RMW tail) ----
        CFENCE();
        __syncthreads();
        CFENCE();   // block sinking publishes below / hoisting flag above
        if (tid == 0)
            __hip_atomic_store(&myflags[ng], (unsigned)(t + 1), __ATOMIC_RELAXED,
                               __HIP_MEMORY_SCOPE_AGENT);
    }
}

// ---------------- fallback path (tiny ws): multi-launch steps ----------------
__global__ __launch_bounds__(256) void h0wh(const float* __restrict__ Wh,
                                            const float* __restrict__ h0,
                                            float* __restrict__ c) {
    const int g = blockIdx.x;
    const int n = threadIdx.x * 4;
    float4 a = {0.f, 0.f, 0.f, 0.f};
    for (int kk = 0; kk < 16; ++kk) {
        int k = g * 16 + kk;
        float hv = h0[k];
        float4 w = *(const float4*)(Wh + (size_t)k * HH + n);
        a.x += hv * w.x; a.y += hv * w.y; a.z += hv * w.z; a.w += hv * w.w;
    }
    atomicAdd(&c[n + 0], a.x);
    atomicAdd(&c[n + 1], a.y);
    atomicAdd(&c[n + 2], a.z);
    atomicAdd(&c[n + 3], a.w);
}

__global__ __launch_bounds__(256) void t0_kernel(float* __restrict__ out,
                                                 const float* __restrict__ c) {
    const int idx = blockIdx.x * 256 + threadIdx.x;
    const int b = idx >> 10;
    const int n = idx & 1023;
    const size_t p = (size_t)b * SS * HH + n;
    out[p] = tanhf(out[p] + c[n]);
}

__global__ __launch_bounds__(256) void rnn_step(const float* __restrict__ Wh,
                                                float* __restrict__ out, int t) {
    __shared__ float hsl[8][1028];
    __shared__ float ps[256];
    const int tid = threadIdx.x;
    const int n0 = blockIdx.x * 16;
    const int b0 = blockIdx.y * 8;
    for (int i = tid; i < 8 * 256; i += 256) {
        int r = i >> 8;
        int c = (i & 255) << 2;
        *(float4*)&hsl[r][c] =
            *(const float4*)(out + ((size_t)(b0 + r) * SS + (t - 1)) * HH + c);
    }
    __syncthreads();
    const int nl = tid & 15;
    const int bl = (tid >> 4) & 7;
    const int half_ = tid >> 7;
    const int n = n0 + nl;
    float acc = 0.f;
    const float* hrow = &hsl[bl][half_ * 512];
    const float* wcol = Wh + (size_t)(half_ * 512) * HH + n;
#pragma unroll 4
    for (int k = 0; k < 512; k += 4) {
        float4 h4 = *(const float4*)(hrow + k);
        acc += h4.x * wcol[(size_t)(k + 0) * HH];
        acc += h4.y * wcol[(size_t)(k + 1) * HH];
        acc += h4.z * wcol[(size_t)(k + 2) * HH];
        acc += h4.w * wcol[(size_t)(k + 3) * HH];
    }
    ps[tid] = acc;
    __syncthreads();
    if (tid < 128) {
        const size_t obase = ((size_t)(b0 + bl) * SS + t) * HH + n;
        out[obase] = tanhf(out[obase] + ps[tid] + ps[tid + 128]);
    }
}

extern "C" void kernel_launch(void* const* d_in, const int* in_sizes, int n_in,
                              void* d_out, int out_size, void* d_ws, size_t ws_size,
                              hipStream_t stream) {
    const float* x    = (const float*)d_in[0];
    const float* Wx   = (const float*)d_in[1];
    const float* Wh   = (const float*)d_in[2];
    const float* bias = (const float*)d_in[3];
    const float* h0   = (const float*)d_in[4];
    float* out = (float*)d_out;
    float* ws  = (float*)d_ws;

    // Phase 1: Xp = x@Wx + b -> d_out
    xw_gemm<<<dim3(8, 256), 256, 0, stream>>>(x, Wx, bias, out);

    // ws layout: [0..511] flags (uint) | [512..] hbuf 2*32*1024 f | WhT 1024^2 f
    const size_t need_persist = (size_t)(512 + 2 * BB * HH) * sizeof(float);
    const size_t need_wht     = need_persist + (size_t)HH * HH * sizeof(float);

    if (ws_size >= need_persist) {
        unsigned int* flags = (unsigned int*)ws;
        float* hbuf = ws + 512;
        hipMemsetAsync(flags, 0, 2048, stream);

        const float* WhT = nullptr;
        if (ws_size >= need_wht) {
            float* whtp = ws + 512 + 2 * BB * HH;
            transpose_wh<<<dim3(32, 32), 256, 0, stream>>>(Wh, whtp);
            WhT = whtp;
        }

        void* kargs[] = {(void*)&Wh, (void*)&WhT, (void*)&h0, (void*)&out,
                         (void*)&flags, (void*)&hbuf};
        hipError_t rc = hipLaunchCooperativeKernel((const void*)rnn_persist,
                                                   dim3(WGN), dim3(256), kargs, 0,
                                                   stream);
        if (rc != hipSuccess) {
            rnn_persist<<<dim3(WGN), dim3(256), 0, stream>>>(Wh, WhT, h0, out,
                                                             flags, hbuf);
        }
    } else {
        // emergency fallback: multi-launch (correct, slow)
        float* cvec = ws;  // 1024 floats
        hipMemsetAsync(cvec, 0, HH * sizeof(float), stream);
        h0wh<<<64, 256, 0, stream>>>(Wh, h0, cvec);
        t0_kernel<<<BB * HH / 256, 256, 0, stream>>>(out, cvec);
        for (int t = 1; t < SS; ++t)
            rnn_step<<<dim3(64, 4), 256, 0, stream>>>(Wh, out, t);
    }
}

// Round 16
// 4860.601 us; speedup vs baseline: 1.2574x; 1.0823x over previous
//
#include <hip/hip_runtime.h>
#include <hip/hip_bf16.h>

// RNN: h_t = tanh(x_t @ Wx + h_{t-1} @ Wh + b), B=32, S=1024, D=H=1024, fp32.
// Phase 1: Xp = x@Wx + b in-place into d_out (~87% of fp32 vector peak).
// Phase 2: ONE persistent kernel, 8 chains x 32 WGs x (4b x 32n).
// R16: BIT30 TAG-IN-DATA. h = tanh(.) in [-1,1] -> bit30 of every published
//   float is 0. Steal it: publisher sets bit30 = (t>>1)&1; consumer polls the
//   DATA WORDS until both halves of each ull carry the expected parity, then
//   clears bit30 (exact). Validity is atomic WITHIN each word -> no ack, no
//   flag, no separate stage: critical path = publish commit + one poll batch
//   (~1.5 MALL RTs vs R12/R15's 4). R10's two killers fixed: no traffic
//   doubling (stolen bit), batched 8-wide parallel re-poll (not per-word
//   dependent spins). Zero ordering assumptions: hoisted/stale polls simply
//   fail parity and retry. 2-slot ping-pong induction bounds skew<2 steps so
//   parity (t>>1)&1 disambiguates; cross-launch staleness erased by memset
//   0xFF (bit30=1 = stale). NaN impossible (finite inputs).

#define BB 32
#define SS 1024
#define DD 1024
#define HH 1024
#define NG 32   // n-groups of 32 cols
#define BG 8    // b-groups (chains) of 4 batches
#define WGN (NG * BG)

typedef unsigned long long ull;

#define ALD(p) __hip_atomic_load((p), __ATOMIC_RELAXED, __HIP_MEMORY_SCOPE_AGENT)

// ---------------- Phase 1: C = A @ W + bias ----------------
__global__ __launch_bounds__(256) void xw_gemm(const float* __restrict__ A,
                                               const float* __restrict__ W,
                                               const float* __restrict__ bias,
                                               float* __restrict__ C) {
    __shared__ float As[8][132];
    __shared__ float Bs[8][132];
    const int tid = threadIdx.x;
    const int n0 = blockIdx.x * 128;
    const int m0 = blockIdx.y * 128;
    const int tx = tid & 15;
    const int ty = tid >> 4;
    const int ar = tid >> 1;
    const int ak = (tid & 1) * 4;
    const int bk = tid >> 5;
    const int bn = (tid & 31) * 4;

    float acc[8][8];
#pragma unroll
    for (int i = 0; i < 8; ++i)
#pragma unroll
        for (int j = 0; j < 8; ++j) acc[i][j] = 0.f;

    for (int k0 = 0; k0 < DD; k0 += 8) {
        float4 av = *(const float4*)(A + (size_t)(m0 + ar) * DD + k0 + ak);
        float4 bv = *(const float4*)(W + (size_t)(k0 + bk) * HH + n0 + bn);
        __syncthreads();
        As[ak + 0][ar] = av.x;
        As[ak + 1][ar] = av.y;
        As[ak + 2][ar] = av.z;
        As[ak + 3][ar] = av.w;
        *(float4*)&Bs[bk][bn] = bv;
        __syncthreads();
#pragma unroll
        for (int k = 0; k < 8; ++k) {
            float4 a0 = *(const float4*)&As[k][ty * 4];
            float4 a1 = *(const float4*)&As[k][64 + ty * 4];
            float4 b0 = *(const float4*)&Bs[k][tx * 4];
            float4 b1 = *(const float4*)&Bs[k][64 + tx * 4];
            float ar_[8] = {a0.x, a0.y, a0.z, a0.w, a1.x, a1.y, a1.z, a1.w};
            float br_[8] = {b0.x, b0.y, b0.z, b0.w, b1.x, b1.y, b1.z, b1.w};
#pragma unroll
            for (int i = 0; i < 8; ++i)
#pragma unroll
                for (int j = 0; j < 8; ++j)
                    acc[i][j] = fmaf(ar_[i], br_[j], acc[i][j]);
        }
    }

    float4 bv0 = *(const float4*)(bias + n0 + tx * 4);
    float4 bv1 = *(const float4*)(bias + n0 + 64 + tx * 4);
#pragma unroll
    for (int i = 0; i < 8; ++i) {
        int m = m0 + ((i < 4) ? (ty * 4 + i) : (64 + ty * 4 + (i - 4)));
        float4 r0 = {acc[i][0] + bv0.x, acc[i][1] + bv0.y,
                     acc[i][2] + bv0.z, acc[i][3] + bv0.w};
        float4 r1 = {acc[i][4] + bv1.x, acc[i][5] + bv1.y,
                     acc[i][6] + bv1.z, acc[i][7] + bv1.w};
        *(float4*)(C + (size_t)m * HH + n0 + tx * 4) = r0;
        *(float4*)(C + (size_t)m * HH + n0 + 64 + tx * 4) = r1;
    }
}

// ---------------- WhT[n][k] = Wh[k][n] ----------------
__global__ __launch_bounds__(256) void transpose_wh(const float* __restrict__ in,
                                                    float* __restrict__ outT) {
    __shared__ float tile[32][33];
    const int tx = threadIdx.x & 31;
    const int ty = threadIdx.x >> 5;
    const int x0 = blockIdx.x * 32;
    const int y0 = blockIdx.y * 32;
    for (int r = ty; r < 32; r += 8)
        tile[r][tx] = in[(size_t)(y0 + r) * HH + x0 + tx];
    __syncthreads();
    for (int r = ty; r < 32; r += 8)
        outT[(size_t)(x0 + r) * HH + y0 + tx] = tile[tx][r];
}

// ---------------- Persistent RNN over all S steps ----------------
// WG(bg,ng): batches b0..b0+3, cols n0..n0+31. Thread tile 4b x 16n x 8k:
//   ns = tid>>7 (col half of 16), kq = tid&127 -> k in {4kq..+3} u {512+4kq..+3}.
#define FMA_HALF(HALF)                                                         \
    {                                                                          \
        const int kb = (HALF) * 512 + kq * 4;                                  \
        float4 h[4];                                                           \
        _Pragma("unroll") for (int b = 0; b < 4; ++b)                          \
            h[b] = *(const float4*)&hs[b][kb];                                 \
        _Pragma("unroll") for (int b = 0; b < 4; ++b)                          \
            _Pragma("unroll") for (int c = 0; c < 16; ++c)                     \
                a[b * 16 + c] += h[b].x * wreg[HALF][c].x +                    \
                                 h[b].y * wreg[HALF][c].y +                    \
                                 h[b].z * wreg[HALF][c].z +                    \
                                 h[b].w * wreg[HALF][c].w;                     \
    }

__global__ __launch_bounds__(256, 1) void rnn_persist(
    const float* __restrict__ Wh, const float* __restrict__ WhT,
    const float* __restrict__ h0, float* __restrict__ out,
    float* __restrict__ hbuf) {
    __shared__ float hs[4][1024];    // 16KB [b][k]
    __shared__ float red[4][64];
    __shared__ float hout[4][32];    // linearized h tile for coalesced publish

    const int tid  = threadIdx.x;
    const int ng   = blockIdx.x & 31;
    const int bg   = blockIdx.x >> 5;
    const int n0   = ng * 32;
    const int b0   = bg * 4;
    const int lane = tid & 63;
    const int wv   = tid >> 6;
    const int ns   = tid >> 7;
    const int kq   = tid & 127;

    const ull TAGMASK = ~((1ull << 30) | (1ull << 62));

    // --- one-time: this thread's Wh fragment into registers ---
    float4 wreg[2][16];
    if (WhT) {
        const float* base = WhT + (size_t)(n0 + ns * 16) * HH + kq * 4;
#pragma unroll
        for (int c = 0; c < 16; ++c) {
            wreg[0][c] = *(const float4*)(base + (size_t)c * HH);
            wreg[1][c] = *(const float4*)(base + (size_t)c * HH + 512);
        }
    } else {
#pragma unroll
        for (int c = 0; c < 16; ++c) {
            float v[8];
            for (int j = 0; j < 4; ++j)
                v[j] = Wh[(size_t)(kq * 4 + j) * HH + n0 + ns * 16 + c];
            for (int j = 0; j < 4; ++j)
                v[4 + j] = Wh[(size_t)(512 + kq * 4 + j) * HH + n0 + ns * 16 + c];
            wreg[0][c] = {v[0], v[1], v[2], v[3]};
            wreg[1][c] = {v[4], v[5], v[6], v[7]};
        }
    }

    // epilogue mapping: thread (tid<128) owns output (eb, ec)
    size_t xp_base = 0;
    int eb = 0, ec = 0;
    if (tid < 128) {
        int l   = tid & 63;
        int idx = (int)(__brev((unsigned)l) >> 26);  // 6-bit bit-reverse
        eb = idx >> 4;                                // 0..3
        ec = (tid >> 6) * 16 + (idx & 15);            // 0..31
        xp_base = ((size_t)(b0 + eb) * SS) * HH + (n0 + ec);
    }

    for (int t = 0; t < SS; ++t) {
        // ---- prefetch own Xp (plain load, independent of sync) ----
        float xp = 0.f;
        if (tid < 128) xp = out[xp_base + (size_t)t * HH];

        float a[64];
#pragma unroll
        for (int i = 0; i < 64; ++i) a[i] = 0.f;

        if (t == 0) {
#pragma unroll
            for (int j = 0; j < 4; ++j) {
                int f4 = tid + 256 * j;
                int r = f4 >> 8, c4 = (f4 & 255) * 4;
                *(float4*)&hs[r][c4] = *(const float4*)(h0 + c4);
            }
            __syncthreads();
            FMA_HALF(0)
            FMA_HALF(1)
        } else {
            // ---- tag-in-data poll: batched 8-load re-issue until all 16
            //      floats carry parity ((t-1)>>1)&1. Data arrives WITH the
            //      successful poll -> no flag RT, no separate stage RT. ----
            const ull* hsrc = (const ull*)hbuf + (size_t)((t - 1) & 1) * BB * 512;
            const unsigned pc = ((unsigned)(t - 1) >> 1) & 1u;
            ull w[8];
            for (;;) {
#pragma unroll
                for (int j = 0; j < 4; ++j)
                    w[j] = ALD(hsrc + (size_t)(b0 + j) * 512 + tid);
#pragma unroll
                for (int j = 0; j < 4; ++j)
                    w[4 + j] = ALD(hsrc + (size_t)(b0 + j) * 512 + 256 + tid);
                unsigned bad = 0;
#pragma unroll
                for (int j = 0; j < 8; ++j) {
                    bad |= (((unsigned)(w[j] >> 30)) ^ pc) & 1u;
                    bad |= (((unsigned)(w[j] >> 62)) ^ pc) & 1u;
                }
                if (!bad) break;
            }
#pragma unroll
            for (int j = 0; j < 4; ++j) {
                *(ull*)&hs[j][tid * 2] = w[j] & TAGMASK;
                *(ull*)&hs[j][512 + tid * 2] = w[4 + j] & TAGMASK;
            }
            __syncthreads();
            FMA_HALF(0)
            FMA_HALF(1)
        }

        // ---- folding in-wave reduce over kq ----
        int s = 64;
#pragma unroll
        for (int m = 1; m <= 32; m <<= 1) {
            const int hs_ = s >> 1;
            const bool hi = (lane & m) != 0;
#pragma unroll
            for (int i = 0; i < hs_; ++i) {
                float lo = a[i], hg = a[i + hs_];
                a[i]       = hi ? hg : lo;
                a[i + hs_] = hi ? lo : hg;
            }
#pragma unroll
            for (int i = 0; i < hs_; ++i) a[i] += __shfl_xor(a[i + hs_], m, 64);
            s = hs_;
        }

        red[wv][lane] = a[0];
        __syncthreads();

        // ---- epilogue: finalize, write out (plain), linearize into hout ----
        if (tid < 128) {
            const int l = tid & 63;
            const int nss = tid >> 6;
            float v = red[nss * 2][l] + red[nss * 2 + 1][l];
            float hv = tanhf(v + xp);
            out[xp_base + (size_t)t * HH] = hv;  // plain (write-only in-kernel)
            hout[eb][ec] = hv;
        }
        __syncthreads();

        // ---- publish: 64 contiguous 8B stores, bit30 of each float = step
        //      parity (t>>1)&1. Validity rides inside the word: no ack, no
        //      flag. |h|<=1 -> bit30 is 0 pre-tag (exact recovery on read). ----
        if (tid < 64) {
            const int r  = tid >> 4;   // 0..3
            const int c2 = tid & 15;   // 0..15 (x2 floats = 32 cols)
            const ull pp = (ull)(((unsigned)t >> 1) & 1u);
            ull u = *(const ull*)&hout[r][c2 * 2];
            u |= (pp << 30) | (pp << 62);
            __hip_atomic_store(
                (ull*)hbuf + (size_t)(t & 1) * BB * 512 +
                    (size_t)(b0 + r) * 512 + (n0 >> 1) + c2,
                u, __ATOMIC_RELAXED, __HIP_MEMORY_SCOPE_AGENT);
        }
        // no barrier needed: next step's poll self-validates; publishes are
        // issued in-order before this wave's next poll.
    }
}

// ---------------- fallback path (tiny ws): multi-launch steps ----------------
__global__ __launch_bounds__(256) void h0wh(const float* __restrict__ Wh,
                                            const float* __restrict__ h0,
                                            float* __restrict__ c) {
    const int g = blockIdx.x;
    const int n = threadIdx.x * 4;
    float4 a = {0.f, 0.f, 0.f, 0.f};
    for (int kk = 0; kk < 16; ++kk) {
        int k = g * 16 + kk;
        float hv = h0[k];
        float4 w = *(const float4*)(Wh + (size_t)k * HH + n);
        a.x += hv * w.x; a.y += hv * w.y; a.z += hv * w.z; a.w += hv * w.w;
    }
    atomicAdd(&c[n + 0], a.x);
    atomicAdd(&c[n + 1], a.y);
    atomicAdd(&c[n + 2], a.z);
    atomicAdd(&c[n + 3], a.w);
}

__global__ __launch_bounds__(256) void t0_kernel(float* __restrict__ out,
                                                 const float* __restrict__ c) {
    const int idx = blockIdx.x * 256 + threadIdx.x;
    const int b = idx >> 10;
    const int n = idx & 1023;
    const size_t p = (size_t)b * SS * HH + n;
    out[p] = tanhf(out[p] + c[n]);
}

__global__ __launch_bounds__(256) void rnn_step(const float* __restrict__ Wh,
                                                float* __restrict__ out, int t) {
    __shared__ float hsl[8][1028];
    __shared__ float ps[256];
    const int tid = threadIdx.x;
    const int n0 = blockIdx.x * 16;
    const int b0 = blockIdx.y * 8;
    for (int i = tid; i < 8 * 256; i += 256) {
        int r = i >> 8;
        int c = (i & 255) << 2;
        *(float4*)&hsl[r][c] =
            *(const float4*)(out + ((size_t)(b0 + r) * SS + (t - 1)) * HH + c);
    }
    __syncthreads();
    const int nl = tid & 15;
    const int bl = (tid >> 4) & 7;
    const int half_ = tid >> 7;
    const int n = n0 + nl;
    float acc = 0.f;
    const float* hrow = &hsl[bl][half_ * 512];
    const float* wcol = Wh + (size_t)(half_ * 512) * HH + n;
#pragma unroll 4
    for (int k = 0; k < 512; k += 4) {
        float4 h4 = *(const float4*)(hrow + k);
        acc += h4.x * wcol[(size_t)(k + 0) * HH];
        acc += h4.y * wcol[(size_t)(k + 1) * HH];
        acc += h4.z * wcol[(size_t)(k + 2) * HH];
        acc += h4.w * wcol[(size_t)(k + 3) * HH];
    }
    ps[tid] = acc;
    __syncthreads();
    if (tid < 128) {
        const size_t obase = ((size_t)(b0 + bl) * SS + t) * HH + n;
        out[obase] = tanhf(out[obase] + ps[tid] + ps[tid + 128]);
    }
}

extern "C" void kernel_launch(void* const* d_in, const int* in_sizes, int n_in,
                              void* d_out, int out_size, void* d_ws, size_t ws_size,
                              hipStream_t stream) {
    const float* x    = (const float*)d_in[0];
    const float* Wx   = (const float*)d_in[1];
    const float* Wh   = (const float*)d_in[2];
    const float* bias = (const float*)d_in[3];
    const float* h0   = (const float*)d_in[4];
    float* out = (float*)d_out;
    float* ws  = (float*)d_ws;

    // Phase 1: Xp = x@Wx + b -> d_out
    xw_gemm<<<dim3(8, 256), 256, 0, stream>>>(x, Wx, bias, out);

    // ws layout: hbuf 2*32*1024 floats (256 KB, tag-in-data) | WhT 1024^2 f
    const size_t need_persist = (size_t)(2 * BB * HH) * sizeof(float);
    const size_t need_wht     = need_persist + (size_t)HH * HH * sizeof(float);

    if (ws_size >= need_persist) {
        float* hbuf = ws;
        // erase stale tags from prior launches/poison: 0xFF -> bit30=1 = stale
        hipMemsetAsync(hbuf, 0xFF, need_persist, stream);

        const float* WhT = nullptr;
        if (ws_size >= need_wht) {
            float* whtp = ws + 2 * BB * HH;
            transpose_wh<<<dim3(32, 32), 256, 0, stream>>>(Wh, whtp);
            WhT = whtp;
        }

        void* kargs[] = {(void*)&Wh, (void*)&WhT, (void*)&h0, (void*)&out,
                         (void*)&hbuf};
        hipError_t rc = hipLaunchCooperativeKernel((const void*)rnn_persist,
                                                   dim3(WGN), dim3(256), kargs, 0,
                                                   stream);
        if (rc != hipSuccess) {
            rnn_persist<<<dim3(WGN), dim3(256), 0, stream>>>(Wh, WhT, h0, out,
                                                             hbuf);
        }
    } else {
        // emergency fallback: multi-launch (correct, slow)
        float* cvec = ws;  // 1024 floats
        hipMemsetAsync(cvec, 0, HH * sizeof(float), stream);
        h0wh<<<64, 256, 0, stream>>>(Wh, h0, cvec);
        t0_kernel<<<BB * HH / 256, 256, 0, stream>>>(out, cvec);
        for (int t = 1; t < SS; ++t)
            rnn_step<<<dim3(64, 4), 256, 0, stream>>>(Wh, out, t);
    }
}